// Round 3
// baseline (91.298 us; speedup 1.0000x reference)
//
#include <hip/hip_runtime.h>
#include <math.h>

#define B_N 4096
#define L_N 16
#define NJC 32            // default j-chunks (grid.y)
#define CSTRIDE 48        // floats per j coefficient record: [0:16)=A [16:32)=B [32:48)=C

#define NHALF_LOG2E 0.7213475204444817f   // 0.5 * log2(e)
#define LOG2E_F     1.4426950408889634f
#define LN2_F       0.6931471805599453f
#define LOG_2PI_F   1.8378770664093453f

typedef float f32x2 __attribute__((ext_vector_type(2)));

// ws layout (floats):
//   coef:     [B_N][CSTRIDE]           (786 KB)
//   partials: [njc][17][B_N]           field 0..15 = per-l exp2 sums, 16 = sum2

// ---- coefficient precompute: logq2(i,j,l) = A*z^2 + B*z + C (log2 domain) ----
extern "C" __global__ __launch_bounds__(256)
void btc_coef(const float* __restrict__ zm, const float* __restrict__ zlv,
              float* __restrict__ coef) {
    const int g = blockIdx.x * 256 + threadIdx.x;   // 65536 = B_N * L_N
    const int j = g >> 4, l = g & 15;
    float M  = zm[g];
    float lv = zlv[g];
    float A  = -NHALF_LOG2E * __builtin_amdgcn_exp2f(-LOG2E_F * lv); // -0.5*log2e*e^-lv
    float Bc = -2.0f * A * M;
    float C  = fmaf(A, M * M, -NHALF_LOG2E * (lv + LOG_2PI_F));
    float* r = coef + (size_t)j * CSTRIDE;
    r[l] = A; r[16 + l] = Bc; r[32 + l] = C;
}

// ---- main: thread owns sample i; j loop-uniform -> coefficients via s_load ----
extern "C" __global__ __launch_bounds__(128, 8)
void btc_main(const float* __restrict__ z, const float* __restrict__ coef,
              float* __restrict__ part, int jc /* j's per chunk */) {
    const int i  = blockIdx.x * 128 + threadIdx.x;
    const int jb = blockIdx.y * jc;

    f32x2 z2[8], u2[8], acc2[8];
    {
        const float4* zr = (const float4*)(z + (size_t)i * L_N);
        #pragma unroll
        for (int q = 0; q < 4; ++q) {
            float4 v = zr[q];
            z2[2*q]   = (f32x2){v.x, v.y};
            z2[2*q+1] = (f32x2){v.z, v.w};
        }
    }
    #pragma unroll
    for (int q = 0; q < 8; ++q) { u2[q] = z2[q] * z2[q]; acc2[q] = (f32x2){0.0f, 0.0f}; }
    float sum2 = 0.0f;   // sum_j exp2(sum_l logq2); diag term bounds it away from total underflow

    const float* cj = coef + (size_t)jb * CSTRIDE;
    for (int jj = 0; jj < jc; ++jj, cj += CSTRIDE) {
        f32x2 sva = {0.0f, 0.0f}, svb = {0.0f, 0.0f};
        #pragma unroll
        for (int q = 0; q < 8; ++q) {
            // uniform scalars -> SGPR pairs; each packed op reads <=1 scalar operand
            f32x2 A  = {cj[2*q],      cj[2*q + 1]};
            f32x2 Bc = {cj[16 + 2*q], cj[16 + 2*q + 1]};
            f32x2 C  = {cj[32 + 2*q], cj[32 + 2*q + 1]};
            f32x2 t  = Bc * z2[q];          // v_pk_mul_f32 (1 sgpr)
            t        = A * u2[q] + t;       // v_pk_fma_f32 (1 sgpr)
            f32x2 lg = t + C;               // v_pk_add_f32 (1 sgpr)
            if (q & 1) svb += lg; else sva += lg;
            f32x2 e;
            e.x = __builtin_amdgcn_exp2f(lg.x);
            e.y = __builtin_amdgcn_exp2f(lg.y);
            acc2[q] += e;
        }
        f32x2 sv = sva + svb;
        sum2 += __builtin_amdgcn_exp2f(sv.x + sv.y);
    }

    float* base = part + (size_t)blockIdx.y * 17 * B_N + i;
    #pragma unroll
    for (int q = 0; q < 8; ++q) {
        base[(size_t)(2*q)     * B_N] = acc2[q].x;
        base[(size_t)(2*q + 1) * B_N] = acc2[q].y;
    }
    base[(size_t)16 * B_N] = sum2;
}

// ---- reduce chunks, finish per-i logs, global sum via one atomic ----
extern "C" __global__ __launch_bounds__(256)
void btc_reduce(const float* __restrict__ part, float* __restrict__ out, int njc) {
    const int tid = threadIdx.x;
    const int i   = blockIdx.x * 256 + tid;

    float accl[L_N];
    #pragma unroll
    for (int l = 0; l < L_N; ++l) accl[l] = 0.0f;
    float sum2 = 0.0f;

    for (int c = 0; c < njc; ++c) {
        const float* b = part + (size_t)c * 17 * B_N + i;
        #pragma unroll
        for (int l = 0; l < L_N; ++l) accl[l] += b[(size_t)l * B_N];
        sum2 += b[(size_t)16 * B_N];
    }

    // natural-log result = ln2 * (log2(sum2) - sum_l log2(accl[l]))
    float lqprod2 = 0.0f;
    #pragma unroll
    for (int l = 0; l < L_N; ++l) lqprod2 += __builtin_amdgcn_logf(accl[l]);
    float v = LN2_F * (__builtin_amdgcn_logf(sum2) - lqprod2);

    #pragma unroll
    for (int off = 32; off > 0; off >>= 1) v += __shfl_down(v, off);
    __shared__ float red[4];
    const int lane = tid & 63, w = tid >> 6;
    if (lane == 0) red[w] = v;
    __syncthreads();
    if (tid == 0)
        atomicAdd(out, ((red[0] + red[1]) + (red[2] + red[3])) * (1.0f / (float)B_N));
}

extern "C" void kernel_launch(void* const* d_in, const int* in_sizes, int n_in,
                              void* d_out, int out_size, void* d_ws, size_t ws_size,
                              hipStream_t stream) {
    const float* z   = (const float*)d_in[0];
    const float* zm  = (const float*)d_in[1];
    const float* zlv = (const float*)d_in[2];
    float* out  = (float*)d_out;
    float* coef = (float*)d_ws;
    float* part = coef + (size_t)B_N * CSTRIDE;

    int njc = NJC;
    while (njc > 1) {
        size_t need = ((size_t)B_N * CSTRIDE + (size_t)njc * 17 * B_N) * sizeof(float);
        if (need <= ws_size) break;
        njc >>= 1;
    }
    const int jc = B_N / njc;

    hipMemsetAsync(out, 0, sizeof(float), stream);   // atomic target; deterministic per call
    hipLaunchKernelGGL(btc_coef, dim3(B_N * L_N / 256), dim3(256), 0, stream, zm, zlv, coef);
    hipLaunchKernelGGL(btc_main, dim3(B_N / 128, njc), dim3(128), 0, stream, z, coef, part, jc);
    hipLaunchKernelGGL(btc_reduce, dim3(B_N / 256), dim3(256), 0, stream, part, out, njc);
}